// Round 15
// baseline (184.399 us; speedup 1.0000x reference)
//
#include <hip/hip_runtime.h>

#define HW 65536

typedef __attribute__((ext_vector_type(8))) short short8;
typedef __attribute__((ext_vector_type(4))) float float4v;

__device__ __forceinline__ int refl(int i){ if (i < 0) i = -i; if (i > 255) i = 510 - i; return i; }
__device__ __forceinline__ float lrelu(float x){ return x > 0.f ? x : 0.01f * x; }
__device__ __forceinline__ unsigned int f2bf(float x){
  union { float f; unsigned int u; } v; v.f = x;
  unsigned int r = v.u + 0x7fff + ((v.u >> 16) & 1);
  return r >> 16;
}

// ---------------- K1: bilinear grid sample (border, align_corners=False) ----------------
__global__ __launch_bounds__(256) void k_gridsample(const float* __restrict__ img,
                                                    const float* __restrict__ zern,
                                                    float* __restrict__ tilt){
  int x = threadIdx.x, y = blockIdx.x;
  int pix = y * 256 + x;
  float px = zern[pix * 35 + 0], py = zern[pix * 35 + 1];
  float ix = ((float)x + px) * (256.f / 255.f) - 0.5f;
  float iy = ((float)y + py) * (256.f / 255.f) - 0.5f;
  ix = fminf(fmaxf(ix, 0.f), 255.f);
  iy = fminf(fmaxf(iy, 0.f), 255.f);
  float x0f = floorf(ix), y0f = floorf(iy);
  float wx = ix - x0f, wy = iy - y0f;
  int x0 = (int)x0f, y0 = (int)y0f;
  int x1 = min(x0 + 1, 255), y1 = min(y0 + 1, 255);
  #pragma unroll
  for (int c = 0; c < 3; ++c){
    const float* im = img + c * HW;
    float g00 = im[y0 * 256 + x0], g01 = im[y0 * 256 + x1];
    float g10 = im[y1 * 256 + x0], g11 = im[y1 * 256 + x1];
    float top = g00 * (1.f - wx) + g01 * wx;
    float bot = g10 * (1.f - wx) + g11 * wx;
    tilt[c * HW + pix] = top * (1.f - wy) + bot * wy;
  }
}

// ---------------- Weight convert: fp32 -> zero-padded bf16 ------------------------------
#define W2OFF 13312
#define W3OFF 59904
__global__ __launch_bounds__(256) void k_wcvt(const float* __restrict__ w1,
    const float* __restrict__ w2, const float* __restrict__ w3,
    unsigned short* __restrict__ wbf){
  int i = blockIdx.x * 256 + threadIdx.x;
  if (i < 208 * 64){
    int n = i >> 6, k = i & 63;
    float v = (n < 200 && k < 33) ? w1[n * 33 + k] : 0.f;
    wbf[i] = (unsigned short)f2bf(v);
  } else if (i < W2OFF + 208 * 224){
    int j = i - W2OFF; int n = j / 224, k = j - n * 224;
    float v = (n < 200 && k < 200) ? w2[n * 200 + k] : 0.f;
    wbf[i] = (unsigned short)f2bf(v);
  } else if (i < 84992){
    int j = i - W3OFF; int n = j / 224, k = j - n * 224;
    float v = (n < 100 && k < 200) ? w3[n * 200 + k] : 0.f;
    wbf[i] = (unsigned short)f2bf(v);
  }
}

// ---------------- Toeplitz tables: 30 x 16 x 96 bf16 = 92 KB ----------------------------
// t<10: bl col t (vconv);  10..19: mu col t-10;  20..29: br col t-20 (hconv).
__global__ __launch_bounds__(256) void k_tz(const float* __restrict__ bl,
    const float* __restrict__ br, const float* __restrict__ mu,
    unsigned short* __restrict__ Tt){
  int e = blockIdx.x * 256 + threadIdx.x;
  if (e >= 46080) return;
  int t = e / 1536, rem = e - t * 1536;
  int m = rem / 96, k = rem - m * 96;
  int d = k - m;
  float v = 0.f;
  if (d >= 0 && d <= 64){
    if (t < 10)      v = bl[d * 10 + t];
    else if (t < 20) v = mu[d * 10 + (t - 10)];
    else             v = br[d * 10 + (t - 20)];
  }
  Tt[e] = (unsigned short)f2bf(v);
}

// ---------------- Fused MLP: 32-pixel tile, 3 layers, MFMA bf16 -------------------------
#define HSTR 232
__global__ __launch_bounds__(256) void k_mlp(const float* __restrict__ zern,
    const float* __restrict__ b1f, const float* __restrict__ b2f,
    const float* __restrict__ b3f, const unsigned short* __restrict__ wbf,
    float* __restrict__ coefp){
  __shared__ char smem[29696];
  unsigned short* H1 = (unsigned short*)smem;
  float*          H3 = (float*)smem;
  unsigned short* XB = (unsigned short*)(smem + 14848);
  unsigned short* H2 = XB;
  int tid = threadIdx.x;
  int pix0 = blockIdx.x * 32;
  int lane = tid & 63, wv = tid >> 6;
  int ln = lane & 15, qd = lane >> 4;

  for (int e = tid; e < 1152; e += 256) ((int*)XB)[e] = 0;
  for (int e = tid; e < 384; e += 256){
    int m = e / 12, j = e - m * 12;
    ((int*)H1)[m * 116 + 104 + j] = 0;
  }
  __syncthreads();
  for (int e = tid; e < 32 * 33; e += 256){
    int m = e / 33, k = e - m * 33;
    XB[m * 72 + k] = (unsigned short)f2bf(zern[(pix0 + m) * 35 + 2 + k]);
  }
  __syncthreads();

  // ---- layer 1 ----
  for (int nt = wv; nt < 13; nt += 4){
    int n = nt * 16 + ln;
    short8 b0 = *(const short8*)(wbf + n * 64 + qd * 8);
    short8 b1 = *(const short8*)(wbf + n * 64 + 32 + qd * 8);
    float bv = (n < 200) ? b1f[n] : 0.f;
    #pragma unroll
    for (int mt = 0; mt < 2; ++mt){
      float4v acc = {bv, bv, bv, bv};
      short8 a0 = *(const short8*)(XB + (mt * 16 + ln) * 72 + qd * 8);
      short8 a1 = *(const short8*)(XB + (mt * 16 + ln) * 72 + 32 + qd * 8);
      acc = __builtin_amdgcn_mfma_f32_16x16x32_bf16(a0, b0, acc, 0, 0, 0);
      acc = __builtin_amdgcn_mfma_f32_16x16x32_bf16(a1, b1, acc, 0, 0, 0);
      #pragma unroll
      for (int r = 0; r < 4; ++r)
        H1[(mt * 16 + qd * 4 + r) * HSTR + n] = (unsigned short)f2bf(lrelu(acc[r]));
    }
  }
  __syncthreads();

  // ---- layer 2 ----
  for (int e = tid; e < 384; e += 256){
    int m = e / 12, j = e - m * 12;
    ((int*)H2)[m * 116 + 104 + j] = 0;
  }
  {
    const unsigned short* w2p = wbf + W2OFF;
    for (int nt = wv; nt < 13; nt += 4){
      int n = nt * 16 + ln;
      short8 bf[7];
      #pragma unroll
      for (int kc = 0; kc < 7; ++kc)
        bf[kc] = *(const short8*)(w2p + n * 224 + kc * 32 + qd * 8);
      float bv = (n < 200) ? b2f[n] : 0.f;
      #pragma unroll
      for (int mt = 0; mt < 2; ++mt){
        float4v acc = {bv, bv, bv, bv};
        #pragma unroll
        for (int kc = 0; kc < 7; ++kc){
          short8 af = *(const short8*)(H1 + (mt * 16 + ln) * HSTR + kc * 32 + qd * 8);
          acc = __builtin_amdgcn_mfma_f32_16x16x32_bf16(af, bf[kc], acc, 0, 0, 0);
        }
        #pragma unroll
        for (int r = 0; r < 4; ++r)
          H2[(mt * 16 + qd * 4 + r) * HSTR + n] = (unsigned short)f2bf(lrelu(acc[r]));
      }
    }
  }
  __syncthreads();

  // ---- layer 3 ----
  {
    const unsigned short* w3p = wbf + W3OFF;
    for (int nt = wv; nt < 7; nt += 4){
      int n = nt * 16 + ln;
      short8 bf[7];
      #pragma unroll
      for (int kc = 0; kc < 7; ++kc)
        bf[kc] = *(const short8*)(w3p + n * 224 + kc * 32 + qd * 8);
      float bv = (n < 100) ? b3f[n] : 0.f;
      #pragma unroll
      for (int mt = 0; mt < 2; ++mt){
        float4v acc = {bv, bv, bv, bv};
        #pragma unroll
        for (int kc = 0; kc < 7; ++kc){
          short8 af = *(const short8*)(H2 + (mt * 16 + ln) * HSTR + kc * 32 + qd * 8);
          acc = __builtin_amdgcn_mfma_f32_16x16x32_bf16(af, bf[kc], acc, 0, 0, 0);
        }
        #pragma unroll
        for (int r = 0; r < 4; ++r)
          H3[(mt * 16 + qd * 4 + r) * 113 + n] = acc[r];
      }
    }
  }
  __syncthreads();

  for (int e = tid; e < 3200; e += 256){
    int n = e >> 5, m = e & 31;
    coefp[n * HW + pix0 + m] = H3[m * 113 + n];
  }
}

// ---------------- K3 v11: banded-Toeplitz MFMA vconv, i-SPLIT (5 i / block) -------------
// bid < 1280: (c 0..3, j 0..9, ih 0..1, s 0..15): partial over i in [5ih,5ih+5)
//             -> (ih ? sbufB : sbufA)[(c*10+j)]
// bid >= 1280: (c 0..2, s): Smu_{c,m} = A_mu_m . tilt_c, m = 0..9 -> smu
// LDS rows [320,344) zeroed: MFMA reads k up to 95 there with zero A-band — 0*garbage
// would be NaN if leftover bits decode as bf16 Inf/NaN (the r14 failure mode in hconv).
#define VB 344
__global__ __launch_bounds__(256) void k_vconv11(const float* __restrict__ tilt,
    const float* __restrict__ coefp, const unsigned short* __restrict__ Tt,
    float* __restrict__ sbufA, float* __restrict__ sbufB, float* __restrict__ smu){
  __shared__ __align__(16) unsigned short sxb[16 * VB];
  int tid = threadIdx.x;
  int bid = blockIdx.x;
  int lane = tid & 63, wv = tid >> 6;
  int ln = lane & 15, qd = lane >> 4;
  int col = tid & 15, seg = tid >> 4;
  int r0 = seg * 20;

  int goff[20];
  #pragma unroll
  for (int q = 0; q < 20; ++q) goff[q] = refl(r0 + q - 32) * 256 + col;

  for (int e = tid; e < 384; e += 256){
    int cc = e / 24, rp = e - cc * 24;
    sxb[cc * VB + 320 + rp] = 0;
  }

  if (bid < 1280){
    int s = bid & 15;
    int t = bid >> 4;               // 0..79
    int c = t / 20;
    int rem = t - c * 20;
    int j = rem >> 1, ih = rem & 1;
    int i0 = ih * 5;
    int x0 = s * 16;
    float treg[20];
    if (c < 3){
      const float* tc = tilt + c * HW + x0;
      #pragma unroll
      for (int q = 0; q < 20; ++q) treg[q] = tc[goff[q]];
    }
    float pf[20];
    {
      const float* cq = coefp + (i0 * 10 + j) * HW + x0;
      #pragma unroll
      for (int q = 0; q < 20; ++q) pf[q] = cq[goff[q]];
    }
    float4v acc[4];
    #pragma unroll
    for (int t2 = 0; t2 < 4; ++t2) acc[t2] = (float4v){0.f, 0.f, 0.f, 0.f};
    for (int ii = 0; ii < 5; ++ii){
      int i = i0 + ii;
      __syncthreads();
      #pragma unroll
      for (int q = 0; q < 10; ++q){
        float v0 = pf[2 * q], v1 = pf[2 * q + 1];
        if (c < 3){ v0 *= treg[2 * q]; v1 *= treg[2 * q + 1]; }
        unsigned int pk = f2bf(v0) | (f2bf(v1) << 16);
        *(unsigned int*)&sxb[col * VB + r0 + 2 * q] = pk;
      }
      __syncthreads();
      if (ii < 4){
        const float* cn = coefp + ((i + 1) * 10 + j) * HW + x0;
        #pragma unroll
        for (int q = 0; q < 20; ++q) pf[q] = cn[goff[q]];
      }
      const unsigned short* ta = Tt + i * 1536 + ln * 96 + qd * 8;
      short8 A0 = *(const short8*)(ta);
      short8 A1 = *(const short8*)(ta + 32);
      short8 A2 = *(const short8*)(ta + 64);
      #pragma unroll
      for (int t2 = 0; t2 < 4; ++t2){
        int yt = wv * 4 + t2;
        const unsigned short* bp = sxb + ln * VB + yt * 16 + qd * 8;
        short8 B0 = *(const short8*)(bp);
        short8 B1 = *(const short8*)(bp + 32);
        short8 B2 = *(const short8*)(bp + 64);
        acc[t2] = __builtin_amdgcn_mfma_f32_16x16x32_bf16(A0, B0, acc[t2], 0, 0, 0);
        acc[t2] = __builtin_amdgcn_mfma_f32_16x16x32_bf16(A1, B1, acc[t2], 0, 0, 0);
        acc[t2] = __builtin_amdgcn_mfma_f32_16x16x32_bf16(A2, B2, acc[t2], 0, 0, 0);
      }
    }
    float* S = (ih ? sbufB : sbufA) + (c * 10 + j) * HW + x0 + ln;
    #pragma unroll
    for (int t2 = 0; t2 < 4; ++t2){
      int yt = wv * 4 + t2;
      #pragma unroll
      for (int r = 0; r < 4; ++r)
        S[(yt * 16 + qd * 4 + r) * 256] = acc[t2][r];
    }
  } else {
    int b2 = bid - 1280;
    int c = b2 >> 4, s = b2 & 15;
    int x0 = s * 16;
    const float* tc = tilt + c * HW + x0;
    float tv[20];
    #pragma unroll
    for (int q = 0; q < 20; ++q) tv[q] = tc[goff[q]];
    #pragma unroll
    for (int q = 0; q < 10; ++q){
      unsigned int pk = f2bf(tv[2 * q]) | (f2bf(tv[2 * q + 1]) << 16);
      *(unsigned int*)&sxb[col * VB + r0 + 2 * q] = pk;
    }
    __syncthreads();
    for (int m = 0; m < 10; ++m){
      const unsigned short* ta = Tt + (10 + m) * 1536 + ln * 96 + qd * 8;
      short8 A0 = *(const short8*)(ta);
      short8 A1 = *(const short8*)(ta + 32);
      short8 A2 = *(const short8*)(ta + 64);
      float4v acc[4];
      #pragma unroll
      for (int t2 = 0; t2 < 4; ++t2) acc[t2] = (float4v){0.f, 0.f, 0.f, 0.f};
      #pragma unroll
      for (int t2 = 0; t2 < 4; ++t2){
        int yt = wv * 4 + t2;
        const unsigned short* bp = sxb + ln * VB + yt * 16 + qd * 8;
        short8 B0 = *(const short8*)(bp);
        short8 B1 = *(const short8*)(bp + 32);
        short8 B2 = *(const short8*)(bp + 64);
        acc[t2] = __builtin_amdgcn_mfma_f32_16x16x32_bf16(A0, B0, acc[t2], 0, 0, 0);
        acc[t2] = __builtin_amdgcn_mfma_f32_16x16x32_bf16(A1, B1, acc[t2], 0, 0, 0);
        acc[t2] = __builtin_amdgcn_mfma_f32_16x16x32_bf16(A2, B2, acc[t2], 0, 0, 0);
      }
      float* S = smu + (c * 10 + m) * HW + x0 + ln;
      #pragma unroll
      for (int t2 = 0; t2 < 4; ++t2){
        int yt = wv * 4 + t2;
        #pragma unroll
        for (int r = 0; r < 4; ++r)
          S[(yt * 16 + qd * 4 + r) * 256] = acc[t2][r];
      }
    }
  }
}

// ---------------- K4 v9b: Toeplitz-MFMA hconv, ONE plane-conv per block -----------------
// 1120 blocks = 70 plane-units x 16 y-tiles. unit u<40: (tgt=u/10, col=u%10), input
// A+B partial sum, taps br (Tt 20+col). u>=40: smu plane u-40, taps mu (Tt 10+col).
// R14 NaN FIX: stride 344 (all B reads in-bounds) + cols [320,344) ZEROED — the k>=80
// band has zero A coefficients, but MFMA 0*garbage = NaN when stale LDS bits decode
// as bf16 Inf/NaN. Same guard the vconv kernels always had.
#define HS2 344
__global__ __launch_bounds__(256) void k_hconv9(const float* __restrict__ sbufA,
    const float* __restrict__ sbufB, const float* __restrict__ smu,
    const unsigned short* __restrict__ Tt, float* __restrict__ part2){
  __shared__ __align__(16) unsigned short sxb[16 * HS2];
  int tid = threadIdx.x;
  int grp = blockIdx.x >> 4;
  int yt  = blockIdx.x & 15;
  int y0 = yt * 16;
  int lane = tid & 63, wv = tid >> 6;
  int ln = lane & 15, qd = lane >> 4;
  int srow = tid >> 4, scol = tid & 15;

  // zero tail cols [320,344) of every row
  for (int e = tid; e < 384; e += 256){
    int rr = e / 24, cp = e - rr * 24;
    sxb[rr * HS2 + 320 + cp] = 0;
  }

  int gx[20];
  #pragma unroll
  for (int q = 0; q < 20; ++q) gx[q] = refl(scol * 20 - 32 + q);

  if (grp < 40){
    const float* pa = sbufA + grp * HW + (y0 + srow) * 256;
    const float* pb = sbufB + grp * HW + (y0 + srow) * 256;
    #pragma unroll
    for (int q = 0; q < 10; ++q){
      float v0 = pa[gx[2 * q]]     + pb[gx[2 * q]];
      float v1 = pa[gx[2 * q + 1]] + pb[gx[2 * q + 1]];
      *(unsigned int*)&sxb[srow * HS2 + scol * 20 + 2 * q] = f2bf(v0) | (f2bf(v1) << 16);
    }
  } else {
    const float* pm = smu + (grp - 40) * HW + (y0 + srow) * 256;
    #pragma unroll
    for (int q = 0; q < 10; ++q){
      float v0 = pm[gx[2 * q]], v1 = pm[gx[2 * q + 1]];
      *(unsigned int*)&sxb[srow * HS2 + scol * 20 + 2 * q] = f2bf(v0) | (f2bf(v1) << 16);
    }
  }
  __syncthreads();
  int colk = (grp < 40) ? (grp % 10) : ((grp - 40) % 10);
  int tbase = (grp < 40) ? 20 : 10;
  const unsigned short* ta = Tt + (tbase + colk) * 1536 + ln * 96 + qd * 8;
  short8 A0 = *(const short8*)(ta);
  short8 A1 = *(const short8*)(ta + 32);
  short8 A2 = *(const short8*)(ta + 64);
  #pragma unroll
  for (int t = 0; t < 4; ++t){
    int wt = wv * 4 + t;
    const unsigned short* bp = sxb + ln * HS2 + wt * 16 + qd * 8;
    short8 B0 = *(const short8*)(bp);
    short8 B1 = *(const short8*)(bp + 32);
    short8 B2 = *(const short8*)(bp + 64);
    float4v acc = {0.f, 0.f, 0.f, 0.f};
    acc = __builtin_amdgcn_mfma_f32_16x16x32_bf16(A0, B0, acc, 0, 0, 0);
    acc = __builtin_amdgcn_mfma_f32_16x16x32_bf16(A1, B1, acc, 0, 0, 0);
    acc = __builtin_amdgcn_mfma_f32_16x16x32_bf16(A2, B2, acc, 0, 0, 0);
    float4 res = {acc[0], acc[1], acc[2], acc[3]};
    *(float4*)(part2 + grp * HW + (y0 + ln) * 256 + wt * 16 + qd * 4) = res;
  }
}

// ---------------- K5: reduce 70 part2 planes -> out ------------------------------------
// den = sum part2[30..39] + muC ; num_c = sum part2[c*10..+9] + sum part2[40+c*10..+9]
__global__ __launch_bounds__(256) void k_final(const float* __restrict__ part2,
                                               const float* __restrict__ mu,
                                               float* __restrict__ out){
  int pix = blockIdx.x * 256 + threadIdx.x;
  float muC = 0.f;
  #pragma unroll
  for (int m = 0; m < 10; ++m){
    float s = 0.f;
    for (int u = 0; u < 65; ++u) s += mu[u * 10 + m];
    muC += s * s;
  }
  float den = muC;
  #pragma unroll
  for (int q = 0; q < 10; ++q) den += part2[(30 + q) * HW + pix];
  float inv = 1.f / den;
  #pragma unroll
  for (int c = 0; c < 3; ++c){
    float s = 0.f;
    #pragma unroll
    for (int q = 0; q < 10; ++q)
      s += part2[(c * 10 + q) * HW + pix] + part2[(40 + c * 10 + q) * HW + pix];
    out[c * HW + pix] = s * inv;
  }
}

extern "C" void kernel_launch(void* const* d_in, const int* in_sizes, int n_in,
                              void* d_out, int out_size, void* d_ws, size_t ws_size,
                              hipStream_t stream) {
  const float* img  = (const float*)d_in[0];
  const float* zern = (const float*)d_in[1];
  const float* w1   = (const float*)d_in[2];
  const float* b1   = (const float*)d_in[3];
  const float* w2   = (const float*)d_in[4];
  const float* b2   = (const float*)d_in[5];
  const float* w3   = (const float*)d_in[6];
  const float* b3   = (const float*)d_in[7];
  const float* bl   = (const float*)d_in[8];
  const float* br   = (const float*)d_in[9];
  const float* mu   = (const float*)d_in[10];
  float* out = (float*)d_out;

  float* w     = (float*)d_ws;
  float* tilt  = w;              // planes [0,3)
  float* coefp = w + 3 * HW;     // planes [3,103); dead after vconv11
  float* part2 = w + 3 * HW;     // planes [3,73): per-plane hconv partials (reuse coefp)
  float* sbufA = w + 103 * HW;   // planes [103,143)
  float* sbufB = w + 143 * HW;   // planes [143,183)
  float* smu   = w + 183 * HW;   // planes [183,213)
  unsigned short* wbf = (unsigned short*)sbufA;          // dead before vconv11 writes
  unsigned short* Tt  = (unsigned short*)(w + 213 * HW); // Toeplitz tables, 92 KB

  k_gridsample<<<256, 256, 0, stream>>>(img, zern, tilt);
  k_wcvt<<<332, 256, 0, stream>>>(w1, w2, w3, wbf);
  k_tz<<<180, 256, 0, stream>>>(bl, br, mu, Tt);
  k_mlp<<<2048, 256, 0, stream>>>(zern, b1, b2, b3, wbf, coefp);
  k_vconv11<<<1328, 256, 0, stream>>>(tilt, coefp, Tt, sbufA, sbufB, smu);
  k_hconv9<<<1120, 256, 0, stream>>>(sbufA, sbufB, smu, Tt, part2);
  k_final<<<256, 256, 0, stream>>>(part2, mu, out);
}

// Round 16
// 178.385 us; speedup vs baseline: 1.0337x; 1.0337x over previous
//
#include <hip/hip_runtime.h>

#define HW 65536

typedef __attribute__((ext_vector_type(8))) short short8;
typedef __attribute__((ext_vector_type(4))) float float4v;

__device__ __forceinline__ int refl(int i){ if (i < 0) i = -i; if (i > 255) i = 510 - i; return i; }
__device__ __forceinline__ float lrelu(float x){ return x > 0.f ? x : 0.01f * x; }
__device__ __forceinline__ unsigned int f2bf(float x){
  union { float f; unsigned int u; } v; v.f = x;
  unsigned int r = v.u + 0x7fff + ((v.u >> 16) & 1);
  return r >> 16;
}

// ---------------- K1: bilinear grid sample (border, align_corners=False) ----------------
__global__ __launch_bounds__(256) void k_gridsample(const float* __restrict__ img,
                                                    const float* __restrict__ zern,
                                                    float* __restrict__ tilt){
  int x = threadIdx.x, y = blockIdx.x;
  int pix = y * 256 + x;
  float px = zern[pix * 35 + 0], py = zern[pix * 35 + 1];
  float ix = ((float)x + px) * (256.f / 255.f) - 0.5f;
  float iy = ((float)y + py) * (256.f / 255.f) - 0.5f;
  ix = fminf(fmaxf(ix, 0.f), 255.f);
  iy = fminf(fmaxf(iy, 0.f), 255.f);
  float x0f = floorf(ix), y0f = floorf(iy);
  float wx = ix - x0f, wy = iy - y0f;
  int x0 = (int)x0f, y0 = (int)y0f;
  int x1 = min(x0 + 1, 255), y1 = min(y0 + 1, 255);
  #pragma unroll
  for (int c = 0; c < 3; ++c){
    const float* im = img + c * HW;
    float g00 = im[y0 * 256 + x0], g01 = im[y0 * 256 + x1];
    float g10 = im[y1 * 256 + x0], g11 = im[y1 * 256 + x1];
    float top = g00 * (1.f - wx) + g01 * wx;
    float bot = g10 * (1.f - wx) + g11 * wx;
    tilt[c * HW + pix] = top * (1.f - wy) + bot * wy;
  }
}

// ---------------- Weight convert: fp32 -> zero-padded bf16 ------------------------------
#define W2OFF 13312
#define W3OFF 59904
__global__ __launch_bounds__(256) void k_wcvt(const float* __restrict__ w1,
    const float* __restrict__ w2, const float* __restrict__ w3,
    unsigned short* __restrict__ wbf){
  int i = blockIdx.x * 256 + threadIdx.x;
  if (i < 208 * 64){
    int n = i >> 6, k = i & 63;
    float v = (n < 200 && k < 33) ? w1[n * 33 + k] : 0.f;
    wbf[i] = (unsigned short)f2bf(v);
  } else if (i < W2OFF + 208 * 224){
    int j = i - W2OFF; int n = j / 224, k = j - n * 224;
    float v = (n < 200 && k < 200) ? w2[n * 200 + k] : 0.f;
    wbf[i] = (unsigned short)f2bf(v);
  } else if (i < 84992){
    int j = i - W3OFF; int n = j / 224, k = j - n * 224;
    float v = (n < 100 && k < 200) ? w3[n * 200 + k] : 0.f;
    wbf[i] = (unsigned short)f2bf(v);
  }
}

// ---------------- Toeplitz tables: 30 x 16 x 96 bf16 = 92 KB ----------------------------
// t<10: bl col t (vconv);  10..19: mu col t-10;  20..29: br col t-20 (hconv).
__global__ __launch_bounds__(256) void k_tz(const float* __restrict__ bl,
    const float* __restrict__ br, const float* __restrict__ mu,
    unsigned short* __restrict__ Tt){
  int e = blockIdx.x * 256 + threadIdx.x;
  if (e >= 46080) return;
  int t = e / 1536, rem = e - t * 1536;
  int m = rem / 96, k = rem - m * 96;
  int d = k - m;
  float v = 0.f;
  if (d >= 0 && d <= 64){
    if (t < 10)      v = bl[d * 10 + t];
    else if (t < 20) v = mu[d * 10 + (t - 10)];
    else             v = br[d * 10 + (t - 20)];
  }
  Tt[e] = (unsigned short)f2bf(v);
}

// ---------------- Fused MLP: 32-pixel tile, 3 layers, MFMA bf16 -------------------------
#define HSTR 232
__global__ __launch_bounds__(256) void k_mlp(const float* __restrict__ zern,
    const float* __restrict__ b1f, const float* __restrict__ b2f,
    const float* __restrict__ b3f, const unsigned short* __restrict__ wbf,
    float* __restrict__ coefp){
  __shared__ char smem[29696];
  unsigned short* H1 = (unsigned short*)smem;
  float*          H3 = (float*)smem;
  unsigned short* XB = (unsigned short*)(smem + 14848);
  unsigned short* H2 = XB;
  int tid = threadIdx.x;
  int pix0 = blockIdx.x * 32;
  int lane = tid & 63, wv = tid >> 6;
  int ln = lane & 15, qd = lane >> 4;

  for (int e = tid; e < 1152; e += 256) ((int*)XB)[e] = 0;
  for (int e = tid; e < 384; e += 256){
    int m = e / 12, j = e - m * 12;
    ((int*)H1)[m * 116 + 104 + j] = 0;
  }
  __syncthreads();
  for (int e = tid; e < 32 * 33; e += 256){
    int m = e / 33, k = e - m * 33;
    XB[m * 72 + k] = (unsigned short)f2bf(zern[(pix0 + m) * 35 + 2 + k]);
  }
  __syncthreads();

  // ---- layer 1 ----
  for (int nt = wv; nt < 13; nt += 4){
    int n = nt * 16 + ln;
    short8 b0 = *(const short8*)(wbf + n * 64 + qd * 8);
    short8 b1 = *(const short8*)(wbf + n * 64 + 32 + qd * 8);
    float bv = (n < 200) ? b1f[n] : 0.f;
    #pragma unroll
    for (int mt = 0; mt < 2; ++mt){
      float4v acc = {bv, bv, bv, bv};
      short8 a0 = *(const short8*)(XB + (mt * 16 + ln) * 72 + qd * 8);
      short8 a1 = *(const short8*)(XB + (mt * 16 + ln) * 72 + 32 + qd * 8);
      acc = __builtin_amdgcn_mfma_f32_16x16x32_bf16(a0, b0, acc, 0, 0, 0);
      acc = __builtin_amdgcn_mfma_f32_16x16x32_bf16(a1, b1, acc, 0, 0, 0);
      #pragma unroll
      for (int r = 0; r < 4; ++r)
        H1[(mt * 16 + qd * 4 + r) * HSTR + n] = (unsigned short)f2bf(lrelu(acc[r]));
    }
  }
  __syncthreads();

  // ---- layer 2 ----
  for (int e = tid; e < 384; e += 256){
    int m = e / 12, j = e - m * 12;
    ((int*)H2)[m * 116 + 104 + j] = 0;
  }
  {
    const unsigned short* w2p = wbf + W2OFF;
    for (int nt = wv; nt < 13; nt += 4){
      int n = nt * 16 + ln;
      short8 bf[7];
      #pragma unroll
      for (int kc = 0; kc < 7; ++kc)
        bf[kc] = *(const short8*)(w2p + n * 224 + kc * 32 + qd * 8);
      float bv = (n < 200) ? b2f[n] : 0.f;
      #pragma unroll
      for (int mt = 0; mt < 2; ++mt){
        float4v acc = {bv, bv, bv, bv};
        #pragma unroll
        for (int kc = 0; kc < 7; ++kc){
          short8 af = *(const short8*)(H1 + (mt * 16 + ln) * HSTR + kc * 32 + qd * 8);
          acc = __builtin_amdgcn_mfma_f32_16x16x32_bf16(af, bf[kc], acc, 0, 0, 0);
        }
        #pragma unroll
        for (int r = 0; r < 4; ++r)
          H2[(mt * 16 + qd * 4 + r) * HSTR + n] = (unsigned short)f2bf(lrelu(acc[r]));
      }
    }
  }
  __syncthreads();

  // ---- layer 3 ----
  {
    const unsigned short* w3p = wbf + W3OFF;
    for (int nt = wv; nt < 7; nt += 4){
      int n = nt * 16 + ln;
      short8 bf[7];
      #pragma unroll
      for (int kc = 0; kc < 7; ++kc)
        bf[kc] = *(const short8*)(w3p + n * 224 + kc * 32 + qd * 8);
      float bv = (n < 100) ? b3f[n] : 0.f;
      #pragma unroll
      for (int mt = 0; mt < 2; ++mt){
        float4v acc = {bv, bv, bv, bv};
        #pragma unroll
        for (int kc = 0; kc < 7; ++kc){
          short8 af = *(const short8*)(H2 + (mt * 16 + ln) * HSTR + kc * 32 + qd * 8);
          acc = __builtin_amdgcn_mfma_f32_16x16x32_bf16(af, bf[kc], acc, 0, 0, 0);
        }
        #pragma unroll
        for (int r = 0; r < 4; ++r)
          H3[(mt * 16 + qd * 4 + r) * 113 + n] = acc[r];
      }
    }
  }
  __syncthreads();

  for (int e = tid; e < 3200; e += 256){
    int n = e >> 5, m = e & 31;
    coefp[n * HW + pix0 + m] = H3[m * 113 + n];
  }
}

// ---------------- K3 v12: banded-Toeplitz MFMA vconv, y-HALVES split --------------------
// bid < 1280: (c 0..3, j 0..9, h 0..1, s 0..15): S_{c,j} rows [h*128, h*128+128)
//             = Sum_i A_i . X_{c,i10+j}  (full i loop; single sbuf — halves write
//             disjoint rows, unlike the i-split which doubled sbuf traffic, R15 lesson).
// bid >= 1280: (c 0..2, h, s): Smu_{c,m} rows half h, m = 0..9 -> smu
// Staged: 192 rows [h*128-32, h*128+160) + zero rows [192,208) (A-band zero for k>=80).
#define VH 208
__global__ __launch_bounds__(256) void k_vconv12(const float* __restrict__ tilt,
    const float* __restrict__ coefp, const unsigned short* __restrict__ Tt,
    float* __restrict__ sbuf, float* __restrict__ smu){
  __shared__ __align__(16) unsigned short sxb[16 * VH];
  int tid = threadIdx.x;
  int bid = blockIdx.x;
  int lane = tid & 63, wv = tid >> 6;
  int ln = lane & 15, qd = lane >> 4;
  int col = tid & 15, seg = tid >> 4;
  int r0 = seg * 12;

  // zero tail rows [192,208): one short per thread (16 cols x 16 rows)
  sxb[(tid & 15) * VH + 192 + (tid >> 4)] = 0;

  if (bid < 1280){
    int s = bid & 15;
    int t = bid >> 4;                 // 0..79
    int c = t / 20;
    int rem = t - c * 20;
    int j = rem >> 1, h = rem & 1;
    int x0 = s * 16;
    int goff[12];
    #pragma unroll
    for (int q = 0; q < 12; ++q)
      goff[q] = refl(h * 128 + r0 + q - 32) * 256 + col;
    float treg[12];
    if (c < 3){
      const float* tc = tilt + c * HW + x0;
      #pragma unroll
      for (int q = 0; q < 12; ++q) treg[q] = tc[goff[q]];
    }
    float pf[12];
    {
      const float* cq = coefp + j * HW + x0;
      #pragma unroll
      for (int q = 0; q < 12; ++q) pf[q] = cq[goff[q]];
    }
    float4v acc[2];
    acc[0] = (float4v){0.f, 0.f, 0.f, 0.f};
    acc[1] = (float4v){0.f, 0.f, 0.f, 0.f};
    for (int i = 0; i < 10; ++i){
      __syncthreads();
      #pragma unroll
      for (int q = 0; q < 6; ++q){
        float v0 = pf[2 * q], v1 = pf[2 * q + 1];
        if (c < 3){ v0 *= treg[2 * q]; v1 *= treg[2 * q + 1]; }
        *(unsigned int*)&sxb[col * VH + r0 + 2 * q] = f2bf(v0) | (f2bf(v1) << 16);
      }
      __syncthreads();
      if (i < 9){
        const float* cn = coefp + ((i + 1) * 10 + j) * HW + x0;
        #pragma unroll
        for (int q = 0; q < 12; ++q) pf[q] = cn[goff[q]];
      }
      const unsigned short* ta = Tt + i * 1536 + ln * 96 + qd * 8;
      short8 A0 = *(const short8*)(ta);
      short8 A1 = *(const short8*)(ta + 32);
      short8 A2 = *(const short8*)(ta + 64);
      #pragma unroll
      for (int t2 = 0; t2 < 2; ++t2){
        int lt = wv * 2 + t2;        // local tile 0..7
        const unsigned short* bp = sxb + ln * VH + lt * 16 + qd * 8;
        short8 B0 = *(const short8*)(bp);
        short8 B1 = *(const short8*)(bp + 32);
        short8 B2 = *(const short8*)(bp + 64);
        acc[t2] = __builtin_amdgcn_mfma_f32_16x16x32_bf16(A0, B0, acc[t2], 0, 0, 0);
        acc[t2] = __builtin_amdgcn_mfma_f32_16x16x32_bf16(A1, B1, acc[t2], 0, 0, 0);
        acc[t2] = __builtin_amdgcn_mfma_f32_16x16x32_bf16(A2, B2, acc[t2], 0, 0, 0);
      }
    }
    float* S = sbuf + (c * 10 + j) * HW + x0 + ln;
    #pragma unroll
    for (int t2 = 0; t2 < 2; ++t2){
      int lt = wv * 2 + t2;
      #pragma unroll
      for (int r = 0; r < 4; ++r)
        S[(h * 128 + lt * 16 + qd * 4 + r) * 256] = acc[t2][r];
    }
  } else {
    int b2 = bid - 1280;              // 0..95
    int c = b2 >> 5;
    int rem = b2 & 31;
    int h = rem >> 4, s = rem & 15;
    int x0 = s * 16;
    const float* tc = tilt + c * HW + x0;
    #pragma unroll
    for (int q = 0; q < 6; ++q){
      float v0 = tc[refl(h * 128 + r0 + 2 * q - 32) * 256 + col];
      float v1 = tc[refl(h * 128 + r0 + 2 * q + 1 - 32) * 256 + col];
      *(unsigned int*)&sxb[col * VH + r0 + 2 * q] = f2bf(v0) | (f2bf(v1) << 16);
    }
    __syncthreads();
    for (int m = 0; m < 10; ++m){
      const unsigned short* ta = Tt + (10 + m) * 1536 + ln * 96 + qd * 8;
      short8 A0 = *(const short8*)(ta);
      short8 A1 = *(const short8*)(ta + 32);
      short8 A2 = *(const short8*)(ta + 64);
      float4v acc[2];
      acc[0] = (float4v){0.f, 0.f, 0.f, 0.f};
      acc[1] = (float4v){0.f, 0.f, 0.f, 0.f};
      #pragma unroll
      for (int t2 = 0; t2 < 2; ++t2){
        int lt = wv * 2 + t2;
        const unsigned short* bp = sxb + ln * VH + lt * 16 + qd * 8;
        short8 B0 = *(const short8*)(bp);
        short8 B1 = *(const short8*)(bp + 32);
        short8 B2 = *(const short8*)(bp + 64);
        acc[t2] = __builtin_amdgcn_mfma_f32_16x16x32_bf16(A0, B0, acc[t2], 0, 0, 0);
        acc[t2] = __builtin_amdgcn_mfma_f32_16x16x32_bf16(A1, B1, acc[t2], 0, 0, 0);
        acc[t2] = __builtin_amdgcn_mfma_f32_16x16x32_bf16(A2, B2, acc[t2], 0, 0, 0);
      }
      float* S = smu + (c * 10 + m) * HW + x0 + ln;
      #pragma unroll
      for (int t2 = 0; t2 < 2; ++t2){
        int lt = wv * 2 + t2;
        #pragma unroll
        for (int r = 0; r < 4; ++r)
          S[(h * 128 + lt * 16 + qd * 4 + r) * 256] = acc[t2][r];
      }
    }
  }
}

// ---------------- K4 v8b: Toeplitz-MFMA hconv, 14 groups x 16 y-tiles -------------------
// HARDENED vs r13: stride 328->344 and zero tail cols [320,344) — ln=15's k=95 read was
// OOB (idx 5255 > 5248); A-band is zero there but 0*Inf garbage = NaN (the r14 bug class).
#define HS2 344
__global__ __launch_bounds__(256) void k_hconv8(const float* __restrict__ sbuf,
    const float* __restrict__ smu, const unsigned short* __restrict__ Tt,
    float* __restrict__ part){
  __shared__ __align__(16) unsigned short sxb[16 * HS2];
  int tid = threadIdx.x;
  int grp = blockIdx.x >> 4;
  int yt  = blockIdx.x & 15;
  int y0 = yt * 16;
  int lane = tid & 63, wv = tid >> 6;
  int ln = lane & 15, qd = lane >> 4;
  int srow = tid >> 4, scol = tid & 15;
  int isbr = (grp < 8);
  int tgt, h;
  if (isbr){ tgt = grp >> 1; h = grp & 1; }
  else     { int g2 = grp - 8; tgt = g2 >> 1; h = g2 & 1; }
  const float* base = isbr ? (sbuf + tgt * 10 * HW) : (smu + tgt * 10 * HW);
  int tbase = isbr ? 20 : 10;

  // zero tail cols [320,344) of every row
  for (int e = tid; e < 384; e += 256){
    int rr = e / 24, cp = e - rr * 24;
    sxb[rr * HS2 + 320 + cp] = 0;
  }

  int gx[20];
  #pragma unroll
  for (int q = 0; q < 20; ++q) gx[q] = refl(scol * 20 - 32 + q);

  float4v acc[4];
  #pragma unroll
  for (int t = 0; t < 4; ++t) acc[t] = (float4v){0.f, 0.f, 0.f, 0.f};

  for (int p = 0; p < 5; ++p){
    int col = h * 5 + p;
    const float* plane = base + col * HW + (y0 + srow) * 256;
    __syncthreads();
    float v[20];
    #pragma unroll
    for (int q = 0; q < 20; ++q) v[q] = plane[gx[q]];
    #pragma unroll
    for (int q = 0; q < 10; ++q){
      *(unsigned int*)&sxb[srow * HS2 + scol * 20 + 2 * q] =
          f2bf(v[2 * q]) | (f2bf(v[2 * q + 1]) << 16);
    }
    __syncthreads();
    const unsigned short* ta = Tt + (tbase + col) * 1536 + ln * 96 + qd * 8;
    short8 A0 = *(const short8*)(ta);
    short8 A1 = *(const short8*)(ta + 32);
    short8 A2 = *(const short8*)(ta + 64);
    #pragma unroll
    for (int t = 0; t < 4; ++t){
      int wt = wv * 4 + t;
      const unsigned short* bp = sxb + ln * HS2 + wt * 16 + qd * 8;
      short8 B0 = *(const short8*)(bp);
      short8 B1 = *(const short8*)(bp + 32);
      short8 B2 = *(const short8*)(bp + 64);
      acc[t] = __builtin_amdgcn_mfma_f32_16x16x32_bf16(A0, B0, acc[t], 0, 0, 0);
      acc[t] = __builtin_amdgcn_mfma_f32_16x16x32_bf16(A1, B1, acc[t], 0, 0, 0);
      acc[t] = __builtin_amdgcn_mfma_f32_16x16x32_bf16(A2, B2, acc[t], 0, 0, 0);
    }
  }
  #pragma unroll
  for (int t = 0; t < 4; ++t){
    int wt = wv * 4 + t;
    float4 res = {acc[t][0], acc[t][1], acc[t][2], acc[t][3]};
    *(float4*)(part + grp * HW + (y0 + ln) * 256 + wt * 16 + qd * 4) = res;
  }
}

// ---------------- K5: out_c = (P2c+P2c+1+P8+2c+P9+2c) / (P6+P7+muC) ---------------------
__global__ __launch_bounds__(256) void k_final(const float* __restrict__ part,
                                               const float* __restrict__ mu,
                                               float* __restrict__ out){
  int pix = blockIdx.x * 256 + threadIdx.x;
  float muC = 0.f;
  #pragma unroll
  for (int m = 0; m < 10; ++m){
    float s = 0.f;
    for (int u = 0; u < 65; ++u) s += mu[u * 10 + m];
    muC += s * s;
  }
  float den = part[6 * HW + pix] + part[7 * HW + pix] + muC;
  float inv = 1.f / den;
  #pragma unroll
  for (int c = 0; c < 3; ++c){
    float num = part[(2 * c) * HW + pix] + part[(2 * c + 1) * HW + pix]
              + part[(8 + 2 * c) * HW + pix] + part[(9 + 2 * c) * HW + pix];
    out[c * HW + pix] = num * inv;
  }
}

extern "C" void kernel_launch(void* const* d_in, const int* in_sizes, int n_in,
                              void* d_out, int out_size, void* d_ws, size_t ws_size,
                              hipStream_t stream) {
  const float* img  = (const float*)d_in[0];
  const float* zern = (const float*)d_in[1];
  const float* w1   = (const float*)d_in[2];
  const float* b1   = (const float*)d_in[3];
  const float* w2   = (const float*)d_in[4];
  const float* b2   = (const float*)d_in[5];
  const float* w3   = (const float*)d_in[6];
  const float* b3   = (const float*)d_in[7];
  const float* bl   = (const float*)d_in[8];
  const float* br   = (const float*)d_in[9];
  const float* mu   = (const float*)d_in[10];
  float* out = (float*)d_out;

  float* w     = (float*)d_ws;
  float* tilt  = w;              // planes [0,3)
  float* coefp = w + 3 * HW;     // planes [3,103); dead after vconv12
  float* part  = w + 3 * HW;     // planes [3,17): hconv partials (reuse coefp region)
  float* sbuf  = w + 103 * HW;   // planes [103,143)
  float* smu   = w + 143 * HW;   // planes [143,173)
  unsigned short* wbf = (unsigned short*)sbuf;           // bf16 weights, dead before vconv12
  unsigned short* Tt  = (unsigned short*)(w + 173 * HW); // Toeplitz tables, 92 KB

  k_gridsample<<<256, 256, 0, stream>>>(img, zern, tilt);
  k_wcvt<<<332, 256, 0, stream>>>(w1, w2, w3, wbf);
  k_tz<<<180, 256, 0, stream>>>(bl, br, mu, Tt);
  k_mlp<<<2048, 256, 0, stream>>>(zern, b1, b2, b3, wbf, coefp);
  k_vconv12<<<1376, 256, 0, stream>>>(tilt, coefp, Tt, sbuf, smu);
  k_hconv8<<<224, 256, 0, stream>>>(sbuf, smu, Tt, part);
  k_final<<<256, 256, 0, stream>>>(part, mu, out);
}

// Round 17
// 169.809 us; speedup vs baseline: 1.0859x; 1.0505x over previous
//
#include <hip/hip_runtime.h>

#define HW 65536

typedef __attribute__((ext_vector_type(8))) short short8;
typedef __attribute__((ext_vector_type(4))) float float4v;

__device__ __forceinline__ int refl(int i){ if (i < 0) i = -i; if (i > 255) i = 510 - i; return i; }
__device__ __forceinline__ float lrelu(float x){ return x > 0.f ? x : 0.01f * x; }
__device__ __forceinline__ unsigned int f2bf(float x){
  union { float f; unsigned int u; } v; v.f = x;
  unsigned int r = v.u + 0x7fff + ((v.u >> 16) & 1);
  return r >> 16;
}

// ---------------- K1: bilinear grid sample (border, align_corners=False) ----------------
__global__ __launch_bounds__(256) void k_gridsample(const float* __restrict__ img,
                                                    const float* __restrict__ zern,
                                                    float* __restrict__ tilt){
  int x = threadIdx.x, y = blockIdx.x;
  int pix = y * 256 + x;
  float px = zern[pix * 35 + 0], py = zern[pix * 35 + 1];
  float ix = ((float)x + px) * (256.f / 255.f) - 0.5f;
  float iy = ((float)y + py) * (256.f / 255.f) - 0.5f;
  ix = fminf(fmaxf(ix, 0.f), 255.f);
  iy = fminf(fmaxf(iy, 0.f), 255.f);
  float x0f = floorf(ix), y0f = floorf(iy);
  float wx = ix - x0f, wy = iy - y0f;
  int x0 = (int)x0f, y0 = (int)y0f;
  int x1 = min(x0 + 1, 255), y1 = min(y0 + 1, 255);
  #pragma unroll
  for (int c = 0; c < 3; ++c){
    const float* im = img + c * HW;
    float g00 = im[y0 * 256 + x0], g01 = im[y0 * 256 + x1];
    float g10 = im[y1 * 256 + x0], g11 = im[y1 * 256 + x1];
    float top = g00 * (1.f - wx) + g01 * wx;
    float bot = g10 * (1.f - wx) + g11 * wx;
    tilt[c * HW + pix] = top * (1.f - wy) + bot * wy;
  }
}

// ---------------- K_prep: weight convert + Toeplitz tables in ONE launch ----------------
// e < 84992: wbf (w1p 208x64 @0; w2p 208x224 @13312; w3p 112x224 @59904)
// e >= 84992: Tt[t][m][k] (30 x 16 x 96; t<10: bl; 10..19: mu; 20..29: br)
#define W2OFF 13312
#define W3OFF 59904
__global__ __launch_bounds__(256) void k_prep(const float* __restrict__ w1,
    const float* __restrict__ w2, const float* __restrict__ w3,
    const float* __restrict__ bl, const float* __restrict__ br,
    const float* __restrict__ mu, unsigned short* __restrict__ wbf,
    unsigned short* __restrict__ Tt){
  int i = blockIdx.x * 256 + threadIdx.x;
  if (i < 84992){
    if (i < 208 * 64){
      int n = i >> 6, k = i & 63;
      float v = (n < 200 && k < 33) ? w1[n * 33 + k] : 0.f;
      wbf[i] = (unsigned short)f2bf(v);
    } else if (i < W2OFF + 208 * 224){
      int j = i - W2OFF; int n = j / 224, k = j - n * 224;
      float v = (n < 200 && k < 200) ? w2[n * 200 + k] : 0.f;
      wbf[i] = (unsigned short)f2bf(v);
    } else {
      int j = i - W3OFF; int n = j / 224, k = j - n * 224;
      float v = (n < 100 && k < 200) ? w3[n * 200 + k] : 0.f;
      wbf[i] = (unsigned short)f2bf(v);
    }
  } else {
    int e = i - 84992;                 // < 46080
    int t = e / 1536, rem = e - t * 1536;
    int m = rem / 96, k = rem - m * 96;
    int d = k - m;
    float v = 0.f;
    if (d >= 0 && d <= 64){
      if (t < 10)      v = bl[d * 10 + t];
      else if (t < 20) v = mu[d * 10 + (t - 10)];
      else             v = br[d * 10 + (t - 20)];
    }
    Tt[e] = (unsigned short)f2bf(v);
  }
}

// ---------------- Fused MLP: 32-pixel tile, 3 layers, MFMA bf16 -------------------------
#define HSTR 232
__global__ __launch_bounds__(256) void k_mlp(const float* __restrict__ zern,
    const float* __restrict__ b1f, const float* __restrict__ b2f,
    const float* __restrict__ b3f, const unsigned short* __restrict__ wbf,
    float* __restrict__ coefp){
  __shared__ char smem[29696];
  unsigned short* H1 = (unsigned short*)smem;
  float*          H3 = (float*)smem;
  unsigned short* XB = (unsigned short*)(smem + 14848);
  unsigned short* H2 = XB;
  int tid = threadIdx.x;
  int pix0 = blockIdx.x * 32;
  int lane = tid & 63, wv = tid >> 6;
  int ln = lane & 15, qd = lane >> 4;

  for (int e = tid; e < 1152; e += 256) ((int*)XB)[e] = 0;
  for (int e = tid; e < 384; e += 256){
    int m = e / 12, j = e - m * 12;
    ((int*)H1)[m * 116 + 104 + j] = 0;
  }
  __syncthreads();
  for (int e = tid; e < 32 * 33; e += 256){
    int m = e / 33, k = e - m * 33;
    XB[m * 72 + k] = (unsigned short)f2bf(zern[(pix0 + m) * 35 + 2 + k]);
  }
  __syncthreads();

  // ---- layer 1 ----
  for (int nt = wv; nt < 13; nt += 4){
    int n = nt * 16 + ln;
    short8 b0 = *(const short8*)(wbf + n * 64 + qd * 8);
    short8 b1 = *(const short8*)(wbf + n * 64 + 32 + qd * 8);
    float bv = (n < 200) ? b1f[n] : 0.f;
    #pragma unroll
    for (int mt = 0; mt < 2; ++mt){
      float4v acc = {bv, bv, bv, bv};
      short8 a0 = *(const short8*)(XB + (mt * 16 + ln) * 72 + qd * 8);
      short8 a1 = *(const short8*)(XB + (mt * 16 + ln) * 72 + 32 + qd * 8);
      acc = __builtin_amdgcn_mfma_f32_16x16x32_bf16(a0, b0, acc, 0, 0, 0);
      acc = __builtin_amdgcn_mfma_f32_16x16x32_bf16(a1, b1, acc, 0, 0, 0);
      #pragma unroll
      for (int r = 0; r < 4; ++r)
        H1[(mt * 16 + qd * 4 + r) * HSTR + n] = (unsigned short)f2bf(lrelu(acc[r]));
    }
  }
  __syncthreads();

  // ---- layer 2 ----
  for (int e = tid; e < 384; e += 256){
    int m = e / 12, j = e - m * 12;
    ((int*)H2)[m * 116 + 104 + j] = 0;
  }
  {
    const unsigned short* w2p = wbf + W2OFF;
    for (int nt = wv; nt < 13; nt += 4){
      int n = nt * 16 + ln;
      short8 bf[7];
      #pragma unroll
      for (int kc = 0; kc < 7; ++kc)
        bf[kc] = *(const short8*)(w2p + n * 224 + kc * 32 + qd * 8);
      float bv = (n < 200) ? b2f[n] : 0.f;
      #pragma unroll
      for (int mt = 0; mt < 2; ++mt){
        float4v acc = {bv, bv, bv, bv};
        #pragma unroll
        for (int kc = 0; kc < 7; ++kc){
          short8 af = *(const short8*)(H1 + (mt * 16 + ln) * HSTR + kc * 32 + qd * 8);
          acc = __builtin_amdgcn_mfma_f32_16x16x32_bf16(af, bf[kc], acc, 0, 0, 0);
        }
        #pragma unroll
        for (int r = 0; r < 4; ++r)
          H2[(mt * 16 + qd * 4 + r) * HSTR + n] = (unsigned short)f2bf(lrelu(acc[r]));
      }
    }
  }
  __syncthreads();

  // ---- layer 3 ----
  {
    const unsigned short* w3p = wbf + W3OFF;
    for (int nt = wv; nt < 7; nt += 4){
      int n = nt * 16 + ln;
      short8 bf[7];
      #pragma unroll
      for (int kc = 0; kc < 7; ++kc)
        bf[kc] = *(const short8*)(w3p + n * 224 + kc * 32 + qd * 8);
      float bv = (n < 100) ? b3f[n] : 0.f;
      #pragma unroll
      for (int mt = 0; mt < 2; ++mt){
        float4v acc = {bv, bv, bv, bv};
        #pragma unroll
        for (int kc = 0; kc < 7; ++kc){
          short8 af = *(const short8*)(H2 + (mt * 16 + ln) * HSTR + kc * 32 + qd * 8);
          acc = __builtin_amdgcn_mfma_f32_16x16x32_bf16(af, bf[kc], acc, 0, 0, 0);
        }
        #pragma unroll
        for (int r = 0; r < 4; ++r)
          H3[(mt * 16 + qd * 4 + r) * 113 + n] = acc[r];
      }
    }
  }
  __syncthreads();

  for (int e = tid; e < 3200; e += 256){
    int n = e >> 5, m = e & 31;
    coefp[n * HW + pix0 + m] = H3[m * 113 + n];
  }
}

// ---------------- K3 v13: banded-Toeplitz MFMA vconv, NON-split, DOUBLE-buffered --------
// Grid shape = r13's vconv10 (the proven optimum: i/x/y splits all regressed, R10/R15/R16).
// New: LDS double buffer -> ONE barrier per i (was 2). Safety: pack(i) targets buf[i&1];
// readers of buf[(i-1)&1] can't be overtaken because no wave passes sync(i+1) while any
// wave still reads buf[i&1]. Tail rows [320,344) of BOTH buffers zeroed (NaN guard).
#define VB 344
__global__ __launch_bounds__(256) void k_vconv13(const float* __restrict__ tilt,
    const float* __restrict__ coefp, const unsigned short* __restrict__ Tt,
    float* __restrict__ sbuf, float* __restrict__ smu){
  __shared__ __align__(16) unsigned short sxb[2][16 * VB];
  int tid = threadIdx.x;
  int bid = blockIdx.x;
  int lane = tid & 63, wv = tid >> 6;
  int ln = lane & 15, qd = lane >> 4;
  int col = tid & 15, seg = tid >> 4;
  int r0 = seg * 20;

  int goff[20];
  #pragma unroll
  for (int q = 0; q < 20; ++q) goff[q] = refl(r0 + q - 32) * 256 + col;

  for (int e = tid; e < 768; e += 256){
    int b = e / 384, r = e - b * 384;
    int cc = r / 24, rp = r - cc * 24;
    sxb[b][cc * VB + 320 + rp] = 0;
  }

  if (bid < 640){
    int s = bid & 15;
    int cj = bid >> 4;
    int c = cj / 10, j = cj - c * 10;
    int x0 = s * 16;
    float treg[20];
    if (c < 3){
      const float* tc = tilt + c * HW + x0;
      #pragma unroll
      for (int q = 0; q < 20; ++q) treg[q] = tc[goff[q]];
    }
    float pf[20];
    {
      const float* cq = coefp + j * HW + x0;
      #pragma unroll
      for (int q = 0; q < 20; ++q) pf[q] = cq[goff[q]];
    }
    float4v acc[4];
    #pragma unroll
    for (int t = 0; t < 4; ++t) acc[t] = (float4v){0.f, 0.f, 0.f, 0.f};
    for (int i = 0; i < 10; ++i){
      int us = i & 1;
      unsigned short* sb = sxb[us];
      #pragma unroll
      for (int q = 0; q < 10; ++q){
        float v0 = pf[2 * q], v1 = pf[2 * q + 1];
        if (c < 3){ v0 *= treg[2 * q]; v1 *= treg[2 * q + 1]; }
        *(unsigned int*)&sb[col * VB + r0 + 2 * q] = f2bf(v0) | (f2bf(v1) << 16);
      }
      __syncthreads();
      if (i < 9){
        const float* cn = coefp + ((i + 1) * 10 + j) * HW + x0;
        #pragma unroll
        for (int q = 0; q < 20; ++q) pf[q] = cn[goff[q]];
      }
      const unsigned short* ta = Tt + i * 1536 + ln * 96 + qd * 8;
      short8 A0 = *(const short8*)(ta);
      short8 A1 = *(const short8*)(ta + 32);
      short8 A2 = *(const short8*)(ta + 64);
      #pragma unroll
      for (int t = 0; t < 4; ++t){
        int yt = wv * 4 + t;
        const unsigned short* bp = sb + ln * VB + yt * 16 + qd * 8;
        short8 B0 = *(const short8*)(bp);
        short8 B1 = *(const short8*)(bp + 32);
        short8 B2 = *(const short8*)(bp + 64);
        acc[t] = __builtin_amdgcn_mfma_f32_16x16x32_bf16(A0, B0, acc[t], 0, 0, 0);
        acc[t] = __builtin_amdgcn_mfma_f32_16x16x32_bf16(A1, B1, acc[t], 0, 0, 0);
        acc[t] = __builtin_amdgcn_mfma_f32_16x16x32_bf16(A2, B2, acc[t], 0, 0, 0);
      }
    }
    float* S = sbuf + (c * 10 + j) * HW + x0 + ln;
    #pragma unroll
    for (int t = 0; t < 4; ++t){
      int yt = wv * 4 + t;
      #pragma unroll
      for (int r = 0; r < 4; ++r)
        S[(yt * 16 + qd * 4 + r) * 256] = acc[t][r];
    }
  } else {
    int b2 = bid - 640;
    int c = b2 >> 4, s = b2 & 15;
    int x0 = s * 16;
    const float* tc = tilt + c * HW + x0;
    float tv[20];
    #pragma unroll
    for (int q = 0; q < 20; ++q) tv[q] = tc[goff[q]];
    #pragma unroll
    for (int q = 0; q < 10; ++q){
      *(unsigned int*)&sxb[0][col * VB + r0 + 2 * q] = f2bf(tv[2 * q]) | (f2bf(tv[2 * q + 1]) << 16);
    }
    __syncthreads();
    for (int m = 0; m < 10; ++m){
      const unsigned short* ta = Tt + (10 + m) * 1536 + ln * 96 + qd * 8;
      short8 A0 = *(const short8*)(ta);
      short8 A1 = *(const short8*)(ta + 32);
      short8 A2 = *(const short8*)(ta + 64);
      float4v acc[4];
      #pragma unroll
      for (int t = 0; t < 4; ++t) acc[t] = (float4v){0.f, 0.f, 0.f, 0.f};
      #pragma unroll
      for (int t = 0; t < 4; ++t){
        int yt = wv * 4 + t;
        const unsigned short* bp = sxb[0] + ln * VB + yt * 16 + qd * 8;
        short8 B0 = *(const short8*)(bp);
        short8 B1 = *(const short8*)(bp + 32);
        short8 B2 = *(const short8*)(bp + 64);
        acc[t] = __builtin_amdgcn_mfma_f32_16x16x32_bf16(A0, B0, acc[t], 0, 0, 0);
        acc[t] = __builtin_amdgcn_mfma_f32_16x16x32_bf16(A1, B1, acc[t], 0, 0, 0);
        acc[t] = __builtin_amdgcn_mfma_f32_16x16x32_bf16(A2, B2, acc[t], 0, 0, 0);
      }
      float* S = smu + (c * 10 + m) * HW + x0 + ln;
      #pragma unroll
      for (int t = 0; t < 4; ++t){
        int yt = wv * 4 + t;
        #pragma unroll
        for (int r = 0; r < 4; ++r)
          S[(yt * 16 + qd * 4 + r) * 256] = acc[t][r];
      }
    }
  }
}

// ---------------- K4 v8b: Toeplitz-MFMA hconv, 14 groups x 16 y-tiles (hardened) --------
#define HS2 344
__global__ __launch_bounds__(256) void k_hconv8(const float* __restrict__ sbuf,
    const float* __restrict__ smu, const unsigned short* __restrict__ Tt,
    float* __restrict__ part){
  __shared__ __align__(16) unsigned short sxb[16 * HS2];
  int tid = threadIdx.x;
  int grp = blockIdx.x >> 4;
  int yt  = blockIdx.x & 15;
  int y0 = yt * 16;
  int lane = tid & 63, wv = tid >> 6;
  int ln = lane & 15, qd = lane >> 4;
  int srow = tid >> 4, scol = tid & 15;
  int isbr = (grp < 8);
  int tgt, h;
  if (isbr){ tgt = grp >> 1; h = grp & 1; }
  else     { int g2 = grp - 8; tgt = g2 >> 1; h = g2 & 1; }
  const float* base = isbr ? (sbuf + tgt * 10 * HW) : (smu + tgt * 10 * HW);
  int tbase = isbr ? 20 : 10;

  for (int e = tid; e < 384; e += 256){
    int rr = e / 24, cp = e - rr * 24;
    sxb[rr * HS2 + 320 + cp] = 0;
  }

  int gx[20];
  #pragma unroll
  for (int q = 0; q < 20; ++q) gx[q] = refl(scol * 20 - 32 + q);

  float4v acc[4];
  #pragma unroll
  for (int t = 0; t < 4; ++t) acc[t] = (float4v){0.f, 0.f, 0.f, 0.f};

  for (int p = 0; p < 5; ++p){
    int col = h * 5 + p;
    const float* plane = base + col * HW + (y0 + srow) * 256;
    __syncthreads();
    float v[20];
    #pragma unroll
    for (int q = 0; q < 20; ++q) v[q] = plane[gx[q]];
    #pragma unroll
    for (int q = 0; q < 10; ++q){
      *(unsigned int*)&sxb[srow * HS2 + scol * 20 + 2 * q] =
          f2bf(v[2 * q]) | (f2bf(v[2 * q + 1]) << 16);
    }
    __syncthreads();
    const unsigned short* ta = Tt + (tbase + col) * 1536 + ln * 96 + qd * 8;
    short8 A0 = *(const short8*)(ta);
    short8 A1 = *(const short8*)(ta + 32);
    short8 A2 = *(const short8*)(ta + 64);
    #pragma unroll
    for (int t = 0; t < 4; ++t){
      int wt = wv * 4 + t;
      const unsigned short* bp = sxb + ln * HS2 + wt * 16 + qd * 8;
      short8 B0 = *(const short8*)(bp);
      short8 B1 = *(const short8*)(bp + 32);
      short8 B2 = *(const short8*)(bp + 64);
      acc[t] = __builtin_amdgcn_mfma_f32_16x16x32_bf16(A0, B0, acc[t], 0, 0, 0);
      acc[t] = __builtin_amdgcn_mfma_f32_16x16x32_bf16(A1, B1, acc[t], 0, 0, 0);
      acc[t] = __builtin_amdgcn_mfma_f32_16x16x32_bf16(A2, B2, acc[t], 0, 0, 0);
    }
  }
  #pragma unroll
  for (int t = 0; t < 4; ++t){
    int wt = wv * 4 + t;
    float4 res = {acc[t][0], acc[t][1], acc[t][2], acc[t][3]};
    *(float4*)(part + grp * HW + (y0 + ln) * 256 + wt * 16 + qd * 4) = res;
  }
}

// ---------------- K5: out_c = (P2c+P2c+1+P8+2c+P9+2c) / (P6+P7+muC) ---------------------
__global__ __launch_bounds__(256) void k_final(const float* __restrict__ part,
                                               const float* __restrict__ mu,
                                               float* __restrict__ out){
  int pix = blockIdx.x * 256 + threadIdx.x;
  float muC = 0.f;
  #pragma unroll
  for (int m = 0; m < 10; ++m){
    float s = 0.f;
    for (int u = 0; u < 65; ++u) s += mu[u * 10 + m];
    muC += s * s;
  }
  float den = part[6 * HW + pix] + part[7 * HW + pix] + muC;
  float inv = 1.f / den;
  #pragma unroll
  for (int c = 0; c < 3; ++c){
    float num = part[(2 * c) * HW + pix] + part[(2 * c + 1) * HW + pix]
              + part[(8 + 2 * c) * HW + pix] + part[(9 + 2 * c) * HW + pix];
    out[c * HW + pix] = num * inv;
  }
}

extern "C" void kernel_launch(void* const* d_in, const int* in_sizes, int n_in,
                              void* d_out, int out_size, void* d_ws, size_t ws_size,
                              hipStream_t stream) {
  const float* img  = (const float*)d_in[0];
  const float* zern = (const float*)d_in[1];
  const float* w1   = (const float*)d_in[2];
  const float* b1   = (const float*)d_in[3];
  const float* w2   = (const float*)d_in[4];
  const float* b2   = (const float*)d_in[5];
  const float* w3   = (const float*)d_in[6];
  const float* b3   = (const float*)d_in[7];
  const float* bl   = (const float*)d_in[8];
  const float* br   = (const float*)d_in[9];
  const float* mu   = (const float*)d_in[10];
  float* out = (float*)d_out;

  float* w     = (float*)d_ws;
  float* tilt  = w;              // planes [0,3)
  float* coefp = w + 3 * HW;     // planes [3,103); dead after vconv13
  float* part  = w + 3 * HW;     // planes [3,17): hconv partials (reuse coefp region)
  float* sbuf  = w + 103 * HW;   // planes [103,143)
  float* smu   = w + 143 * HW;   // planes [143,173)
  unsigned short* wbf = (unsigned short*)sbuf;           // bf16 weights, dead before vconv13
  unsigned short* Tt  = (unsigned short*)(w + 173 * HW); // Toeplitz tables, 92 KB

  k_gridsample<<<256, 256, 0, stream>>>(img, zern, tilt);
  k_prep<<<512, 256, 0, stream>>>(w1, w2, w3, bl, br, mu, wbf, Tt);
  k_mlp<<<2048, 256, 0, stream>>>(zern, b1, b2, b3, wbf, coefp);
  k_vconv13<<<688, 256, 0, stream>>>(tilt, coefp, Tt, sbuf, smu);
  k_hconv8<<<224, 256, 0, stream>>>(sbuf, smu, Tt, part);
  k_final<<<256, 256, 0, stream>>>(part, mu, out);
}